// Round 5
// baseline (1210.156 us; speedup 1.0000x reference)
//
#include <hip/hip_runtime.h>
#include <math.h>

#define B_    4
#define HW1   (130*130)
#define HW2   (132*132)
#define NBUF  ((size_t)B_*128*HW2)
#define EPS_  1e-5f
#define PI_   3.14159265358979f

typedef _Float16 half8 __attribute__((ext_vector_type(8)));
typedef _Float16 half4_ __attribute__((ext_vector_type(4)));
typedef float    float4_ __attribute__((ext_vector_type(4)));

// ============ batched weight pack: fp32 OIHW -> f16 [cc][tap][g][lane][8] ====
// lane=q*16+n ; co=g*16+n ; ci=cc*32+q*8+j  -> A-frag load is 1KB wave-contiguous
struct WPackArgs {
  const float* src[8];
  _Float16*    dst[8];
  int cout[8], cin[8], kk[8];
  int off[9];
};
__global__ void wpack_all(WPackArgs p) {
  int idx = blockIdx.x * blockDim.x + threadIdx.x;
  if (idx >= p.off[8]) return;
  int s = 0;
  while (idx >= p.off[s + 1]) ++s;
  int i = idx - p.off[s];
  int Cin = p.cin[s], K = p.kk[s];
  int KK = K * K, COG = p.cout[s] / 16;
  int j    = i & 7;
  int lane = (i >> 3) & 63;
  int rest = i >> 9;
  int g    = rest % COG; rest /= COG;
  int tap  = rest % KK;
  int cc   = rest / KK;
  int n = lane & 15, q = lane >> 4;
  int co = g * 16 + n;
  int ci = cc * 32 + q * 8 + j;
  p.dst[s][i] = (_Float16)p.src[s][((size_t)co * Cin + ci) * KK + tap];
}

// ============ NCHW f32 -> NHWC f16 (LDS transpose) ============
__global__ void to_nhwc(const float* __restrict__ in, _Float16* __restrict__ out,
                        int C, int HW) {
  __shared__ float t[32][65];
  int b = blockIdx.z, c0 = blockIdx.y * 32, p0 = blockIdx.x * 64;
  int tid = threadIdx.x;
  for (int i = 0; i < 8; ++i) {
    int e = i * 256 + tid; int cl = e >> 6, pl = e & 63;
    int p = p0 + pl;
    float v = 0.f;
    if (p < HW) v = in[((size_t)b * C + c0 + cl) * HW + p];
    t[cl][pl] = v;
  }
  __syncthreads();
  for (int i = 0; i < 8; ++i) {
    int e = i * 256 + tid; int pl = e >> 5, cl = e & 31;
    int p = p0 + pl;
    if (p < HW) out[((size_t)b * HW + p) * C + c0 + cl] = (_Float16)t[cl][pl];
  }
}

__global__ void zerok(float* p, int n) {
  int i = blockIdx.x * blockDim.x + threadIdx.x;
  if (i < n) p[i] = 0.f;
}

// ============ MFMA implicit-GEMM conv ============
// - input affine(+relu) inline from raw sums (AFF:0 none,1 per-(b,c) IN,2 per-c BN)
// - output per-co stats accumulated into sums_out (consumer normalizes inline)
// - kx-outer register blocking: per kx load K+3 row-chunks once (ds_read_b128),
//   run all K ky-taps from registers -> 2.8x less LDS read traffic (K=7)
// - A (weights) rolling 2-deep prefetch across taps (covers L2 latency)
// - cc-chunk LDS double-buffer where 2 bufs fit 64KB static LDS; staging waves
//   own one ci-quad each (wave = q) so affine params are register-resident
template<int CIN, int COUT, int K, int HIN, int HOUT, bool REFLECT, int AFF, bool RELU, bool POB>
__global__ __launch_bounds__(256, 2) void conv_mfma(
    const _Float16* __restrict__ act, const _Float16* __restrict__ wp,
    const float* __restrict__ sums_in, const float* __restrict__ gam,
    const float* __restrict__ bet, float invn, float* __restrict__ sums_out,
    _Float16* __restrict__ out) {
  constexpr int NWC = (COUT >= 64) ? 2 : 1;
  constexpr int WCO = COUT / NWC;            // 64 / 32
  constexpr int MR  = WCO / 16;              // 4 / 2
  constexpr int NWR = 4 / NWC;
  constexpr int ROWS = NWR * 4;              // 8 / 16
  constexpr int PADc = (K - 1) / 2;
  constexpr int IR  = ROWS + K - 1;
  constexpr int XWn = 16 + K - 1;            // needed x width (22 / 18)
  constexpr int XWs = 24;                    // padded chunk stride (128B-aligned rows)
  constexpr int CH  = IR * 4 * XWs;
  constexpr int NBUFS = (2 * CH * 16 <= 59000) ? 2 : 1;
  constexpr int PERQ = IR * XWn;             // staged chunks per wave (one ci-quad)
  constexpr int SMAX = (PERQ + 63) / 64;
  constexpr int NREG = K + 3;
  constexpr int COG = COUT / 16;
  constexpr int KK = K * K;
  constexpr int XT = (HOUT + 15) / 16;
  constexpr int NC = CIN / 32;

  __shared__ half8 smem[NBUFS][CH];
  __shared__ float2 snorm[CIN];
  __shared__ float bsum[COUT * 2];

  const int xt = blockIdx.x % XT, yt = blockIdx.x / XT;
  const int x0 = xt * 16, y0 = yt * ROWS;
  const int b = blockIdx.z;
  const int tid = threadIdx.x;
  const int lane = tid & 63, w = tid >> 6;
  const int wc = (NWC == 2) ? (w & 1) : 0;
  const int wr = (NWC == 2) ? (w >> 1) : w;
  const int n = lane & 15, q = lane >> 4;

  // ---- preamble: inline norm params + zero block stats ----
  if (AFF) {
    if (tid < CIN) {
      int idx = (AFF == 1 ? b * CIN : 0) + tid;
      float m  = sums_in[idx * 2] * invn;
      float vr = sums_in[idx * 2 + 1] * invn - m * m;
      float sc = rsqrtf(vr + EPS_);
      if (AFF == 2) sc *= gam[tid];
      float sh = (AFF == 2 ? bet[tid] : 0.f) - m * sc;
      snorm[tid] = make_float2(sc, sh);
    }
  }
  if (tid < COUT) { bsum[tid * 2] = 0.f; bsum[tid * 2 + 1] = 0.f; }
  __syncthreads();

  float4_ acc[MR][4];
#pragma unroll
  for (int mi = 0; mi < MR; ++mi)
#pragma unroll
    for (int ni = 0; ni < 4; ++ni)
#pragma unroll
      for (int j = 0; j < 4; ++j) acc[mi][ni][j] = 0.f;

  const _Float16* actb = act + (size_t)b * HIN * HIN * CIN;

  // coordinates for staged element s (this wave stages ci-quad = w)
  auto coords = [&](int s, bool& ok, int& iy, int& ix) {
    int row = s / XWn, lx = s % XWn;
    int ty = y0 + row - PADc;
    int tx = x0 + lx - PADc;
    if (REFLECT) {   // P-space; P = reflect_pad1(x), conv pad=1 zeros outside
      ok = (ty >= 0 && ty < HIN + 2 && tx >= 0 && tx < HIN + 2);
      iy = (ty == 0) ? 1 : (ty == HIN + 1 ? HIN - 2 : ty - 1);
      ix = (tx == 0) ? 1 : (tx == HIN + 1 ? HIN - 2 : tx - 1);
    } else {
      ok = (ty >= 0 && ty < HIN && tx >= 0 && tx < HIN);
      iy = ty; ix = tx;
    }
  };
  auto stage_load = [&](int cc, half8* v) {   // issue global loads (no use yet)
#pragma unroll
    for (int i = 0; i < SMAX; ++i) {
      int s = i * 64 + lane;
      half8 t;
#pragma unroll
      for (int j = 0; j < 8; ++j) t[j] = (_Float16)0.f;
      if (s < PERQ) {
        bool ok; int iy, ix;
        coords(s, ok, iy, ix);
        if (ok) t = *(const half8*)(actb + ((size_t)iy * HIN + ix) * CIN + cc * 32 + w * 8);
      }
      v[i] = t;
    }
  };
  auto stage_write = [&](int buf, int cc, half8* v) {
    float nsc[8], nsh[8];
    if (AFF) {
#pragma unroll
      for (int j = 0; j < 8; ++j) {
        float2 t = snorm[cc * 32 + w * 8 + j];
        nsc[j] = t.x; nsh[j] = t.y;
      }
    }
#pragma unroll
    for (int i = 0; i < SMAX; ++i) {
      int s = i * 64 + lane;
      if (s >= PERQ) break;
      int row = s / XWn, lx = s % XWn;
      half8 t = v[i];
      if (AFF) {
        bool ok; int iy, ix;
        coords(s, ok, iy, ix);
        if (ok) {
#pragma unroll
          for (int j = 0; j < 8; ++j) {
            float f = (float)t[j] * nsc[j] + nsh[j];
            if (RELU) f = fmaxf(f, 0.f);
            t[j] = (_Float16)f;
          }
        }
      }
      smem[buf][(row * 4 + w) * XWs + lx] = t;
    }
  };
  auto compute = [&](int buf, int cc) {
    const int R0 = wr * 4;
    half8 areg[2][MR];
    auto ldA = [&](int t, half8* a) {        // t-order: kx outer, ky inner
      int kx = t / K, ky = t % K;
      int tap = ky * K + kx;
#pragma unroll
      for (int mi = 0; mi < MR; ++mi) {
        int g = wc * MR + mi;
        a[mi] = *(const half8*)(wp + (((size_t)(cc * KK + tap) * COG + g) * 64 + lane) * 8);
      }
    };
    ldA(0, areg[0]);
    if (KK > 1) ldA(1, areg[1]);
    half8 breg[NREG];
#pragma unroll
    for (int kx = 0; kx < K; ++kx) {
#pragma unroll
      for (int ri = 0; ri < NREG; ++ri)
        breg[ri] = smem[buf][((R0 + ri) * 4 + q) * XWs + n + kx];
#pragma unroll
      for (int ky = 0; ky < K; ++ky) {
        const int t = kx * K + ky;
#pragma unroll
        for (int mi = 0; mi < MR; ++mi)
#pragma unroll
          for (int ni = 0; ni < 4; ++ni)
            acc[mi][ni] = __builtin_amdgcn_mfma_f32_16x16x32_f16(
                areg[t & 1][mi], breg[ky + ni], acc[mi][ni], 0, 0, 0);
        if (t + 2 < KK) ldA(t + 2, areg[t & 1]);   // refill slot just consumed
      }
    }
  };

  half8 sv[SMAX];
  stage_load(0, sv);
  stage_write(0, 0, sv);
  __syncthreads();
#pragma unroll 1
  for (int cc = 0; cc < NC; ++cc) {
    bool more = (cc + 1 < NC);
    if (NBUFS == 2) {
      if (more) stage_load(cc + 1, sv);      // loads in flight during compute
      compute(cc & 1, cc);
      if (more) { stage_write((cc + 1) & 1, cc + 1, sv); __syncthreads(); }
    } else {
      compute(0, cc);
      if (more) {
        stage_load(cc + 1, sv);              // issue before barrier
        __syncthreads();                     // all waves done reading buf 0
        stage_write(0, cc + 1, sv);
        __syncthreads();
      }
    }
  }

  // ---- epilogue 1: per-co stats from f32 accumulators ----
  const bool xv = (x0 + n) < HOUT;
#pragma unroll
  for (int mi = 0; mi < MR; ++mi) {
#pragma unroll
    for (int j = 0; j < 4; ++j) {
      float s = 0.f, s2 = 0.f;
#pragma unroll
      for (int ni = 0; ni < 4; ++ni) {
        int y = y0 + wr * 4 + ni;
        float f = acc[mi][ni][j];
        bool v = xv && (y < HOUT);
        s  += v ? f : 0.f;
        s2 += v ? f * f : 0.f;
      }
#pragma unroll
      for (int off = 1; off < 16; off <<= 1) {    // reduce across the 16 n-lanes
        s  += __shfl_xor(s,  off, 64);
        s2 += __shfl_xor(s2, off, 64);
      }
      if (n == 0) {
        int co = wc * WCO + mi * 16 + q * 4 + j;
        atomicAdd(&bsum[co * 2],     s);
        atomicAdd(&bsum[co * 2 + 1], s2);
      }
    }
  }
  // ---- epilogue 2: store NHWC f16 (raw conv out; norm applied by consumer) ----
  _Float16* outb = out + (size_t)b * HOUT * HOUT * COUT;
#pragma unroll
  for (int mi = 0; mi < MR; ++mi) {
#pragma unroll
    for (int ni = 0; ni < 4; ++ni) {
      int y = y0 + wr * 4 + ni, x = x0 + n;
      if (y < HOUT && x < HOUT) {
        int co = wc * WCO + mi * 16 + q * 4;
        half4_ h;
#pragma unroll
        for (int j = 0; j < 4; ++j) h[j] = (_Float16)acc[mi][ni][j];
        *(half4_*)(outb + ((size_t)y * HOUT + x) * COUT + co) = h;
      }
    }
  }
  __syncthreads();
  if (tid < COUT) {
    int idx = (POB ? b * COUT : 0) + tid;
    atomicAdd(&sums_out[idx * 2],     bsum[tid * 2]);
    atomicAdd(&sums_out[idx * 2 + 1], bsum[tid * 2 + 1]);
  }
}

// ============ analytic DCT-mean weights ============
__global__ void wdctk(float* __restrict__ wd, int N) {
  int i = blockIdx.x * blockDim.x + threadIdx.x;
  if (i >= N) return;
  float Nf = (float)N;
  float c2 = 0.5f * sqrtf(2.f / Nf);
  float a  = sqrtf(1.f / Nf) - c2;
  float phi = PI_ / (4.f * Nf) * (2.f * i + 1.f);
  float cot = cosf(phi) / sinf(phi);
  wd[i] = a + ((i & 1) ? -c2 : c2) * cot;
}

// ============ md[b][c] += sum_p wd[p]*IN(x)  (inline norm from sums2) ============
__global__ void mdctk(const _Float16* __restrict__ x, const float* __restrict__ wd,
                      const float* __restrict__ sums2, float invn,
                      float* __restrict__ md, int HW) {
  int b = blockIdx.z, tid = threadIdx.x;
  int c = tid & 127, pr = tid >> 7;
  int slab = blockIdx.x, nsl = gridDim.x;
  float m  = sums2[(b * 128 + c) * 2] * invn;
  float sc = rsqrtf(sums2[(b * 128 + c) * 2 + 1] * invn - m * m + EPS_);
  float sh = -m * sc;
  const _Float16* xb = x + (size_t)b * HW * 128;
  float s = 0.f;
  for (int p = slab * 2 + pr; p < HW; p += nsl * 2)
    s += ((float)xb[(size_t)p * 128 + c] * sc + sh) * wd[p];
  __shared__ float l1[256];
  l1[tid] = s;
  __syncthreads();
  if (tid < 128) atomicAdd(&md[b * 128 + c], l1[tid] + l1[tid + 128]);
}

// ============ SFOM gate MLP ============
__global__ void gatek(const float* __restrict__ md, const float* __restrict__ w1,
                      const float* __restrict__ w2, float* __restrict__ gate) {
  __shared__ float t1[4][8];
  int tid = threadIdx.x;
  const float invN = 1.f / (float)HW2;
  if (tid < 32) {
    int b = tid >> 3, r = tid & 7;
    float s = 0.f;
    for (int c = 0; c < 128; ++c) s += md[b * 128 + c] * invN * w1[r * 128 + c];
    t1[b][r] = fmaxf(s, 0.f);
  }
  __syncthreads();
  int b = tid >> 7, c = tid & 127;
  float s = 0.f;
#pragma unroll
  for (int r = 0; r < 8; ++r) s += t1[b][r] * w2[c * 8 + r];
  gate[tid] = 1.f / (1.f + expf(-s));
}

// ============ SFOM apply: xn = IN(x); o = sigmoid(xn*(1+g)/2)*xn ============
__global__ void sfomk(const _Float16* __restrict__ x, const float* __restrict__ sums2,
                      float invn, const float* __restrict__ gate,
                      _Float16* __restrict__ o, int HW) {
  size_t idx = (size_t)blockIdx.x * blockDim.x + threadIdx.x;
  size_t tot = (size_t)4 * HW * 16;
  if (idx >= tot) return;
  int cg = (int)(idx % 16);
  size_t bp = idx / 16;
  int b = (int)(bp / HW);
  half8 v = *(const half8*)(x + bp * 128 + cg * 8);
  half8 r;
#pragma unroll
  for (int j = 0; j < 8; ++j) {
    int c = cg * 8 + j;
    float m  = sums2[(b * 128 + c) * 2] * invn;
    float sc = rsqrtf(sums2[(b * 128 + c) * 2 + 1] * invn - m * m + EPS_);
    float f = (float)v[j] * sc - m * sc;
    float g = gate[b * 128 + c];
    float s = 1.f / (1.f + expf(-(f * (1.f + g) * 0.5f)));
    r[j] = (_Float16)(s * f);
  }
  *(half8*)(o + bp * 128 + cg * 8) = r;
}

// ============ sa = sigmoid(b + sum_c cw[c]*relu(BN(h)))  (inline from sums6) ====
__global__ void sak(const _Float16* __restrict__ h, const float* __restrict__ sums6,
                    float invn, const float* __restrict__ gam, const float* __restrict__ bet,
                    const float* __restrict__ cw, const float* __restrict__ cb,
                    float* __restrict__ sa) {
  __shared__ float ssc[32], ssh[32];
  int tid = threadIdx.x;
  if (tid < 32) {
    float m  = sums6[tid * 2] * invn;
    float sc = rsqrtf(sums6[tid * 2 + 1] * invn - m * m + EPS_) * gam[tid];
    ssc[tid] = sc;
    ssh[tid] = bet[tid] - m * sc;
  }
  __syncthreads();
  int idx = blockIdx.x * blockDim.x + tid;
  if (idx >= 4 * HW2) return;
  const _Float16* p = h + (size_t)idx * 32;
  float s = cb[0];
#pragma unroll
  for (int c = 0; c < 32; ++c)
    s += fmaxf((float)p[c] * ssc[c] + ssh[c], 0.f) * cw[c];
  sa[idx] = 1.f / (1.f + expf(-s));
}

// ============ final: NCHW f32 out = sa * O (NHWC f16), LDS transpose ============
__global__ void finalt(const _Float16* __restrict__ o, const float* __restrict__ sa,
                       float* __restrict__ out) {
  __shared__ float t[32][65];
  int b = blockIdx.z, c0 = blockIdx.y * 32, p0 = blockIdx.x * 64;
  int tid = threadIdx.x;
  for (int i = 0; i < 8; ++i) {
    int e = i * 256 + tid; int pl = e >> 5, cl = e & 31;
    int p = p0 + pl;
    if (p < HW2)
      t[cl][pl] = (float)o[((size_t)b * HW2 + p) * 128 + c0 + cl] * sa[b * HW2 + p];
  }
  __syncthreads();
  for (int i = 0; i < 8; ++i) {
    int e = i * 256 + tid; int cl = e >> 6, pl = e & 63;
    int p = p0 + pl;
    if (p < HW2)
      out[((size_t)b * 128 + c0 + cl) * HW2 + p] = t[cl][pl];
  }
}

extern "C" void kernel_launch(void* const* d_in, const int* in_sizes, int n_in,
                              void* d_out, int out_size, void* d_ws, size_t ws_size,
                              hipStream_t stream) {
  const float* x     = (const float*)d_in[0];
  const float* c1w   = (const float*)d_in[1];
  const float* c2w   = (const float*)d_in[3];
  const float* sa_w1 = (const float*)d_in[5];
  const float* sa_w2 = (const float*)d_in[6];
  const float* dw[6] = {(const float*)d_in[7],  (const float*)d_in[10], (const float*)d_in[13],
                        (const float*)d_in[16], (const float*)d_in[19], (const float*)d_in[22]};
  const float* bg[6] = {(const float*)d_in[8],  (const float*)d_in[11], (const float*)d_in[14],
                        (const float*)d_in[17], (const float*)d_in[20], (const float*)d_in[23]};
  const float* bb[6] = {(const float*)d_in[9],  (const float*)d_in[12], (const float*)d_in[15],
                        (const float*)d_in[18], (const float*)d_in[21], (const float*)d_in[24]};
  const float* cw    = (const float*)d_in[25];
  const float* cb    = (const float*)d_in[26];
  float* out = (float*)d_out;

  // ---- workspace carve ----
  char* wsp = (char*)d_ws;
  auto alloc = [&](size_t bytes) { char* p = wsp; wsp += (bytes + 255) & ~(size_t)255; return p; };
  _Float16* B0 = (_Float16*)alloc(NBUF * 2);
  _Float16* B1 = (_Float16*)alloc(NBUF * 2);
  _Float16* B2 = (_Float16*)alloc(NBUF * 2);
  _Float16* B3 = (_Float16*)alloc(NBUF * 2);
  _Float16* wp_c1 = (_Float16*)alloc((size_t)128 * 128 * 9 * 2);
  _Float16* wp_c2 = (_Float16*)alloc((size_t)128 * 128 * 9 * 2);
  const int sci[6] = {128, 32, 64, 128, 128, 64};
  const int sco[6] = {32, 64, 128, 128, 64, 32};
  _Float16* wp_d[6];
  for (int i = 0; i < 6; ++i) wp_d[i] = (_Float16*)alloc((size_t)sco[i] * sci[i] * 49 * 2);
  float* SUMS = (float*)alloc(8704 * 4);     // 8 layer slots x 1024 + md 512
  float* s_c1 = SUMS;
  float* s_c2 = SUMS + 1024;
  float* s_l[6];
  for (int i = 0; i < 6; ++i) s_l[i] = SUMS + 2048 + i * 1024;
  float* md   = SUMS + 8192;
  float* gate = (float*)alloc(512 * 4);
  float* wd   = (float*)alloc((size_t)HW2 * 4);
  float* sa   = (float*)alloc((size_t)4 * HW2 * 4);

  // ---- batched weight pack (ws re-poisoned each call -> redo) ----
  {
    WPackArgs p;
    p.src[0] = c1w; p.dst[0] = wp_c1; p.cout[0] = 128; p.cin[0] = 128; p.kk[0] = 3;
    p.src[1] = c2w; p.dst[1] = wp_c2; p.cout[1] = 128; p.cin[1] = 128; p.kk[1] = 3;
    for (int i = 0; i < 6; ++i) {
      p.src[2 + i] = dw[i]; p.dst[2 + i] = wp_d[i];
      p.cout[2 + i] = sco[i]; p.cin[2 + i] = sci[i]; p.kk[2 + i] = 7;
    }
    p.off[0] = 0;
    for (int i = 0; i < 8; ++i) p.off[i + 1] = p.off[i] + p.cout[i] * p.cin[i] * p.kk[i] * p.kk[i];
    wpack_all<<<(p.off[8] + 255) / 256, 256, 0, stream>>>(p);
  }

  to_nhwc<<<dim3(16384 / 64, 4, 4), 256, 0, stream>>>(x, B0, 128, 16384);
  zerok<<<34, 256, 0, stream>>>(SUMS, 8704);

  const float i1 = 1.f / (float)HW1, i2 = 1.f / (float)HW2, ib = 1.f / (4.f * HW2);

  // conv1: reflect 3x3, no input norm (bias cancels under IN); stats per-(b,c)
  conv_mfma<128, 128, 3, 128, 130, true, 0, false, true><<<dim3(9 * 17, 1, 4), 256, 0, stream>>>(
      B0, wp_c1, nullptr, nullptr, nullptr, 0.f, s_c1, B1);
  // conv2: stages IN(conv1)+relu inline; stats per-(b,c)
  conv_mfma<128, 128, 3, 130, 132, true, 1, true, true><<<dim3(9 * 17, 1, 4), 256, 0, stream>>>(
      B1, wp_c2, s_c1, nullptr, nullptr, i1, s_c2, B2);

  // SFOM (idct(g*dct(x)) == g*x algebraically; mean_k dct = analytic weights)
  wdctk<<<(HW2 + 255) / 256, 256, 0, stream>>>(wd, HW2);
  mdctk<<<dim3(128, 1, 4), 256, 0, stream>>>(B2, wd, s_c2, i2, md, HW2);
  gatek<<<1, 512, 0, stream>>>(md, sa_w1, sa_w2, gate);
  { size_t tot = (size_t)4 * HW2 * 16;
    sfomk<<<(int)((tot + 255) / 256), 256, 0, stream>>>(B2, s_c2, i2, gate, B3, HW2); }

  // SPEM pyramid: 7x7 convs, each staging applies previous BN+relu inline
  conv_mfma<128, 32, 7, 132, 132, false, 0, false, false><<<dim3(9 * 9, 1, 4), 256, 0, stream>>>(
      B3, wp_d[0], nullptr, nullptr, nullptr, 0.f, s_l[0], B0);
  conv_mfma<32, 64, 7, 132, 132, false, 2, true, false><<<dim3(9 * 17, 1, 4), 256, 0, stream>>>(
      B0, wp_d[1], s_l[0], bg[0], bb[0], ib, s_l[1], B1);
  conv_mfma<64, 128, 7, 132, 132, false, 2, true, false><<<dim3(9 * 17, 1, 4), 256, 0, stream>>>(
      B1, wp_d[2], s_l[1], bg[1], bb[1], ib, s_l[2], B0);
  conv_mfma<128, 128, 7, 132, 132, false, 2, true, false><<<dim3(9 * 17, 1, 4), 256, 0, stream>>>(
      B0, wp_d[3], s_l[2], bg[2], bb[2], ib, s_l[3], B1);
  conv_mfma<128, 64, 7, 132, 132, false, 2, true, false><<<dim3(9 * 17, 1, 4), 256, 0, stream>>>(
      B1, wp_d[4], s_l[3], bg[3], bb[3], ib, s_l[4], B0);
  conv_mfma<64, 32, 7, 132, 132, false, 2, true, false><<<dim3(9 * 9, 1, 4), 256, 0, stream>>>(
      B0, wp_d[5], s_l[4], bg[4], bb[4], ib, s_l[5], B1);

  // spatial attention (L6 BN+relu inline) + final product (NCHW f32 out)
  sak<<<(4 * HW2 + 255) / 256, 256, 0, stream>>>(B1, s_l[5], ib, bg[5], bb[5], cw, cb, sa);
  finalt<<<dim3((HW2 + 63) / 64, 4, 4), 256, 0, stream>>>(B3, sa, out);
}

// Round 6
// 1052.985 us; speedup vs baseline: 1.1493x; 1.1493x over previous
//
#include <hip/hip_runtime.h>
#include <math.h>

#define B_    4
#define HW1   (130*130)
#define HW2   (132*132)
#define NBUF  ((size_t)B_*128*HW2)
#define EPS_  1e-5f
#define PI_   3.14159265358979f

typedef _Float16 half8 __attribute__((ext_vector_type(8)));
typedef _Float16 half4_ __attribute__((ext_vector_type(4)));
typedef float    float4_ __attribute__((ext_vector_type(4)));

// ============ batched weight pack: fp32 OIHW -> f16 [cc][tap][g][lane][8] ====
// lane=q*16+n ; co=g*16+n ; ci=cc*32+q*8+j  -> A-frag load is 1KB wave-contiguous
struct WPackArgs {
  const float* src[8];
  _Float16*    dst[8];
  int cout[8], cin[8], kk[8];
  int off[9];
};
__global__ void wpack_all(WPackArgs p) {
  int idx = blockIdx.x * blockDim.x + threadIdx.x;
  if (idx >= p.off[8]) return;
  int s = 0;
  while (idx >= p.off[s + 1]) ++s;
  int i = idx - p.off[s];
  int Cin = p.cin[s], K = p.kk[s];
  int KK = K * K, COG = p.cout[s] / 16;
  int j    = i & 7;
  int lane = (i >> 3) & 63;
  int rest = i >> 9;
  int g    = rest % COG; rest /= COG;
  int tap  = rest % KK;
  int cc   = rest / KK;
  int n = lane & 15, q = lane >> 4;
  int co = g * 16 + n;
  int ci = cc * 32 + q * 8 + j;
  p.dst[s][i] = (_Float16)p.src[s][((size_t)co * Cin + ci) * KK + tap];
}

// ============ NCHW f32 -> NHWC f16 (LDS transpose) ============
__global__ void to_nhwc(const float* __restrict__ in, _Float16* __restrict__ out,
                        int C, int HW) {
  __shared__ float t[32][65];
  int b = blockIdx.z, c0 = blockIdx.y * 32, p0 = blockIdx.x * 64;
  int tid = threadIdx.x;
  for (int i = 0; i < 8; ++i) {
    int e = i * 256 + tid; int cl = e >> 6, pl = e & 63;
    int p = p0 + pl;
    float v = 0.f;
    if (p < HW) v = in[((size_t)b * C + c0 + cl) * HW + p];
    t[cl][pl] = v;
  }
  __syncthreads();
  for (int i = 0; i < 8; ++i) {
    int e = i * 256 + tid; int pl = e >> 5, cl = e & 31;
    int p = p0 + pl;
    if (p < HW) out[((size_t)b * HW + p) * C + c0 + cl] = (_Float16)t[cl][pl];
  }
}

__global__ void zerok(float* p, int n) {
  int i = blockIdx.x * blockDim.x + threadIdx.x;
  if (i < n) p[i] = 0.f;
}

// ============ MFMA implicit-GEMM conv ============
// R4 structure (stage -> barrier -> compute; single LDS buffer; NO cross-chunk
// register-held loads -- avoids the vmcnt FIFO hazard that sank R5) plus R5's
// kx-outer register blocking: per kx load K+3 row-chunks once (ds_read_b128),
// run all K ky-taps from registers (2.8x less LDS read traffic for K=7).
// A-weights: rolling 2-deep prefetch in kx-outer tap order (only outstanding
// vmem during compute).
template<int CIN, int COUT, int K, int HIN, int HOUT, bool REFLECT, int AFF, bool RELU, bool POB>
__global__ __launch_bounds__(256, 2) void conv_mfma(
    const _Float16* __restrict__ act, const _Float16* __restrict__ wp,
    const float* __restrict__ sums_in, const float* __restrict__ gam,
    const float* __restrict__ bet, float invn, float* __restrict__ sums_out,
    _Float16* __restrict__ out) {
  constexpr int NWC = (COUT >= 64) ? 2 : 1;
  constexpr int WCO = COUT / NWC;            // 64 / 32
  constexpr int MR  = WCO / 16;              // 4 / 2
  constexpr int NWR = 4 / NWC;
  constexpr int ROWS = NWR * 4;              // 8 / 16
  constexpr int PADc = (K - 1) / 2;
  constexpr int IR  = ROWS + K - 1;
  constexpr int XW  = 16 + K - 1;            // 22 / 18
  constexpr int CH  = IR * 4 * XW;           // 16B chunks, idx (row*4+q)*XW+x
  constexpr int NREG = K + 3;
  constexpr int COG = COUT / 16;
  constexpr int KK = K * K;
  constexpr int XT = (HOUT + 15) / 16;

  __shared__ half8 smem[CH];
  __shared__ float2 snorm[CIN];
  __shared__ float bsum[COUT * 2];

  const int xt = blockIdx.x % XT, yt = blockIdx.x / XT;
  const int x0 = xt * 16, y0 = yt * ROWS;
  const int b = blockIdx.z;
  const int tid = threadIdx.x;
  const int lane = tid & 63, w = tid >> 6;
  const int wc = (NWC == 2) ? (w & 1) : 0;
  const int wr = (NWC == 2) ? (w >> 1) : w;
  const int n = lane & 15, q = lane >> 4;

  // ---- preamble: inline norm params + zero block stats ----
  if (AFF) {
    if (tid < CIN) {
      int idx = (AFF == 1 ? b * CIN : 0) + tid;
      float m  = sums_in[idx * 2] * invn;
      float vr = sums_in[idx * 2 + 1] * invn - m * m;
      float sc = rsqrtf(vr + EPS_);
      if (AFF == 2) sc *= gam[tid];
      float sh = (AFF == 2 ? bet[tid] : 0.f) - m * sc;
      snorm[tid] = make_float2(sc, sh);
    }
  }
  if (tid < COUT) { bsum[tid * 2] = 0.f; bsum[tid * 2 + 1] = 0.f; }

  float4_ acc[MR][4];
#pragma unroll
  for (int mi = 0; mi < MR; ++mi)
#pragma unroll
    for (int ni = 0; ni < 4; ++ni)
#pragma unroll
      for (int j = 0; j < 4; ++j) acc[mi][ni][j] = 0.f;

  const _Float16* actb = act + (size_t)b * HIN * HIN * CIN;

  for (int cc = 0; cc < CIN / 32; ++cc) {
    __syncthreads();
    // ---- per-thread norm regs (qq = tid&3 fixed across staging elements) ----
    float nsc[8], nsh[8];
    if (AFF) {
      int cb2 = cc * 32 + (tid & 3) * 8;
#pragma unroll
      for (int j = 0; j < 8; ++j) { float2 t = snorm[cb2 + j]; nsc[j] = t.x; nsh[j] = t.y; }
    }
    // ---- stage (affine+relu applied; borders stay zero = conv zero-pad) ----
    for (int e = tid; e < CH; e += 256) {
      int qq = e & 3, rx = e >> 2;
      int row = rx / XW, lx = rx % XW;
      int ty = y0 + row - PADc;
      int tx = x0 + lx - PADc;
      bool ok; int iy, ix;
      if (REFLECT) {   // P-space; P = reflect_pad1(x), conv pad=1 zeros outside
        ok = (ty >= 0 && ty < HIN + 2 && tx >= 0 && tx < HIN + 2);
        iy = (ty == 0) ? 1 : (ty == HIN + 1 ? HIN - 2 : ty - 1);
        ix = (tx == 0) ? 1 : (tx == HIN + 1 ? HIN - 2 : tx - 1);
      } else {
        ok = (ty >= 0 && ty < HIN && tx >= 0 && tx < HIN);
        iy = ty; ix = tx;
      }
      half8 v;
#pragma unroll
      for (int j = 0; j < 8; ++j) v[j] = (_Float16)0.f;
      if (ok) {
        v = *(const half8*)(actb + ((size_t)iy * HIN + ix) * CIN + cc * 32 + qq * 8);
        if (AFF) {
#pragma unroll
          for (int j = 0; j < 8; ++j) {
            float f = (float)v[j] * nsc[j] + nsh[j];
            if (RELU) f = fmaxf(f, 0.f);
            v[j] = (_Float16)f;
          }
        }
      }
      smem[(row * 4 + qq) * XW + lx] = v;
    }
    __syncthreads();
    // ---- compute: kx-outer register-blocked B; A rolling 2-deep prefetch ----
    {
      const int R0 = wr * 4;
      half8 areg[2][MR];
      auto ldA = [&](int t, half8* a) {        // t-order: kx outer, ky inner
        int kx = t / K, ky = t % K;
        int tap = ky * K + kx;
#pragma unroll
        for (int mi = 0; mi < MR; ++mi) {
          int g = wc * MR + mi;
          a[mi] = *(const half8*)(wp + (((size_t)(cc * KK + tap) * COG + g) * 64 + lane) * 8);
        }
      };
      ldA(0, areg[0]);
      if (KK > 1) ldA(1, areg[1]);
      half8 breg[NREG];
#pragma unroll
      for (int kx = 0; kx < K; ++kx) {
#pragma unroll
        for (int ri = 0; ri < NREG; ++ri)
          breg[ri] = smem[((R0 + ri) * 4 + q) * XW + n + kx];
#pragma unroll
        for (int ky = 0; ky < K; ++ky) {
          const int t = kx * K + ky;
#pragma unroll
          for (int mi = 0; mi < MR; ++mi)
#pragma unroll
            for (int ni = 0; ni < 4; ++ni)
              acc[mi][ni] = __builtin_amdgcn_mfma_f32_16x16x32_f16(
                  areg[t & 1][mi], breg[ky + ni], acc[mi][ni], 0, 0, 0);
          if (t + 2 < KK) ldA(t + 2, areg[t & 1]);   // refill slot just consumed
        }
      }
    }
  }

  // ---- epilogue 1: per-co stats from f32 accumulators ----
  const bool xv = (x0 + n) < HOUT;
#pragma unroll
  for (int mi = 0; mi < MR; ++mi) {
#pragma unroll
    for (int j = 0; j < 4; ++j) {
      float s = 0.f, s2 = 0.f;
#pragma unroll
      for (int ni = 0; ni < 4; ++ni) {
        int y = y0 + wr * 4 + ni;
        float f = acc[mi][ni][j];
        bool v = xv && (y < HOUT);
        s  += v ? f : 0.f;
        s2 += v ? f * f : 0.f;
      }
#pragma unroll
      for (int off = 1; off < 16; off <<= 1) {    // reduce across the 16 n-lanes
        s  += __shfl_xor(s,  off, 64);
        s2 += __shfl_xor(s2, off, 64);
      }
      if (n == 0) {
        int co = wc * WCO + mi * 16 + q * 4 + j;
        atomicAdd(&bsum[co * 2],     s);
        atomicAdd(&bsum[co * 2 + 1], s2);
      }
    }
  }
  // ---- epilogue 2: store NHWC f16 (raw conv out; norm applied by consumer) ----
  _Float16* outb = out + (size_t)b * HOUT * HOUT * COUT;
#pragma unroll
  for (int mi = 0; mi < MR; ++mi) {
#pragma unroll
    for (int ni = 0; ni < 4; ++ni) {
      int y = y0 + wr * 4 + ni, x = x0 + n;
      if (y < HOUT && x < HOUT) {
        int co = wc * WCO + mi * 16 + q * 4;
        half4_ h;
#pragma unroll
        for (int j = 0; j < 4; ++j) h[j] = (_Float16)acc[mi][ni][j];
        *(half4_*)(outb + ((size_t)y * HOUT + x) * COUT + co) = h;
      }
    }
  }
  __syncthreads();
  if (tid < COUT) {
    int idx = (POB ? b * COUT : 0) + tid;
    atomicAdd(&sums_out[idx * 2],     bsum[tid * 2]);
    atomicAdd(&sums_out[idx * 2 + 1], bsum[tid * 2 + 1]);
  }
}

// ============ analytic DCT-mean weights ============
__global__ void wdctk(float* __restrict__ wd, int N) {
  int i = blockIdx.x * blockDim.x + threadIdx.x;
  if (i >= N) return;
  float Nf = (float)N;
  float c2 = 0.5f * sqrtf(2.f / Nf);
  float a  = sqrtf(1.f / Nf) - c2;
  float phi = PI_ / (4.f * Nf) * (2.f * i + 1.f);
  float cot = cosf(phi) / sinf(phi);
  wd[i] = a + ((i & 1) ? -c2 : c2) * cot;
}

// ============ md[b][c] += sum_p wd[p]*IN(x)  (inline norm from sums2) ============
__global__ void mdctk(const _Float16* __restrict__ x, const float* __restrict__ wd,
                      const float* __restrict__ sums2, float invn,
                      float* __restrict__ md, int HW) {
  int b = blockIdx.z, tid = threadIdx.x;
  int c = tid & 127, pr = tid >> 7;
  int slab = blockIdx.x, nsl = gridDim.x;
  float m  = sums2[(b * 128 + c) * 2] * invn;
  float sc = rsqrtf(sums2[(b * 128 + c) * 2 + 1] * invn - m * m + EPS_);
  float sh = -m * sc;
  const _Float16* xb = x + (size_t)b * HW * 128;
  float s = 0.f;
  for (int p = slab * 2 + pr; p < HW; p += nsl * 2)
    s += ((float)xb[(size_t)p * 128 + c] * sc + sh) * wd[p];
  __shared__ float l1[256];
  l1[tid] = s;
  __syncthreads();
  if (tid < 128) atomicAdd(&md[b * 128 + c], l1[tid] + l1[tid + 128]);
}

// ============ SFOM gate MLP ============
__global__ void gatek(const float* __restrict__ md, const float* __restrict__ w1,
                      const float* __restrict__ w2, float* __restrict__ gate) {
  __shared__ float t1[4][8];
  int tid = threadIdx.x;
  const float invN = 1.f / (float)HW2;
  if (tid < 32) {
    int b = tid >> 3, r = tid & 7;
    float s = 0.f;
    for (int c = 0; c < 128; ++c) s += md[b * 128 + c] * invN * w1[r * 128 + c];
    t1[b][r] = fmaxf(s, 0.f);
  }
  __syncthreads();
  int b = tid >> 7, c = tid & 127;
  float s = 0.f;
#pragma unroll
  for (int r = 0; r < 8; ++r) s += t1[b][r] * w2[c * 8 + r];
  gate[tid] = 1.f / (1.f + expf(-s));
}

// ============ SFOM apply: xn = IN(x); o = sigmoid(xn*(1+g)/2)*xn ============
__global__ void sfomk(const _Float16* __restrict__ x, const float* __restrict__ sums2,
                      float invn, const float* __restrict__ gate,
                      _Float16* __restrict__ o, int HW) {
  size_t idx = (size_t)blockIdx.x * blockDim.x + threadIdx.x;
  size_t tot = (size_t)4 * HW * 16;
  if (idx >= tot) return;
  int cg = (int)(idx % 16);
  size_t bp = idx / 16;
  int b = (int)(bp / HW);
  half8 v = *(const half8*)(x + bp * 128 + cg * 8);
  half8 r;
#pragma unroll
  for (int j = 0; j < 8; ++j) {
    int c = cg * 8 + j;
    float m  = sums2[(b * 128 + c) * 2] * invn;
    float sc = rsqrtf(sums2[(b * 128 + c) * 2 + 1] * invn - m * m + EPS_);
    float f = (float)v[j] * sc - m * sc;
    float g = gate[b * 128 + c];
    float s = 1.f / (1.f + expf(-(f * (1.f + g) * 0.5f)));
    r[j] = (_Float16)(s * f);
  }
  *(half8*)(o + bp * 128 + cg * 8) = r;
}

// ============ sa = sigmoid(b + sum_c cw[c]*relu(BN(h)))  (inline from sums6) ====
__global__ void sak(const _Float16* __restrict__ h, const float* __restrict__ sums6,
                    float invn, const float* __restrict__ gam, const float* __restrict__ bet,
                    const float* __restrict__ cw, const float* __restrict__ cb,
                    float* __restrict__ sa) {
  __shared__ float ssc[32], ssh[32];
  int tid = threadIdx.x;
  if (tid < 32) {
    float m  = sums6[tid * 2] * invn;
    float sc = rsqrtf(sums6[tid * 2 + 1] * invn - m * m + EPS_) * gam[tid];
    ssc[tid] = sc;
    ssh[tid] = bet[tid] - m * sc;
  }
  __syncthreads();
  int idx = blockIdx.x * blockDim.x + tid;
  if (idx >= 4 * HW2) return;
  const _Float16* p = h + (size_t)idx * 32;
  float s = cb[0];
#pragma unroll
  for (int c = 0; c < 32; ++c)
    s += fmaxf((float)p[c] * ssc[c] + ssh[c], 0.f) * cw[c];
  sa[idx] = 1.f / (1.f + expf(-s));
}

// ============ final: NCHW f32 out = sa * O (NHWC f16), LDS transpose ============
__global__ void finalt(const _Float16* __restrict__ o, const float* __restrict__ sa,
                       float* __restrict__ out) {
  __shared__ float t[32][65];
  int b = blockIdx.z, c0 = blockIdx.y * 32, p0 = blockIdx.x * 64;
  int tid = threadIdx.x;
  for (int i = 0; i < 8; ++i) {
    int e = i * 256 + tid; int pl = e >> 5, cl = e & 31;
    int p = p0 + pl;
    if (p < HW2)
      t[cl][pl] = (float)o[((size_t)b * HW2 + p) * 128 + c0 + cl] * sa[b * HW2 + p];
  }
  __syncthreads();
  for (int i = 0; i < 8; ++i) {
    int e = i * 256 + tid; int cl = e >> 6, pl = e & 63;
    int p = p0 + pl;
    if (p < HW2)
      out[((size_t)b * 128 + c0 + cl) * HW2 + p] = t[cl][pl];
  }
}

extern "C" void kernel_launch(void* const* d_in, const int* in_sizes, int n_in,
                              void* d_out, int out_size, void* d_ws, size_t ws_size,
                              hipStream_t stream) {
  const float* x     = (const float*)d_in[0];
  const float* c1w   = (const float*)d_in[1];
  const float* c2w   = (const float*)d_in[3];
  const float* sa_w1 = (const float*)d_in[5];
  const float* sa_w2 = (const float*)d_in[6];
  const float* dw[6] = {(const float*)d_in[7],  (const float*)d_in[10], (const float*)d_in[13],
                        (const float*)d_in[16], (const float*)d_in[19], (const float*)d_in[22]};
  const float* bg[6] = {(const float*)d_in[8],  (const float*)d_in[11], (const float*)d_in[14],
                        (const float*)d_in[17], (const float*)d_in[20], (const float*)d_in[23]};
  const float* bb[6] = {(const float*)d_in[9],  (const float*)d_in[12], (const float*)d_in[15],
                        (const float*)d_in[18], (const float*)d_in[21], (const float*)d_in[24]};
  const float* cw    = (const float*)d_in[25];
  const float* cb    = (const float*)d_in[26];
  float* out = (float*)d_out;

  // ---- workspace carve ----
  char* wsp = (char*)d_ws;
  auto alloc = [&](size_t bytes) { char* p = wsp; wsp += (bytes + 255) & ~(size_t)255; return p; };
  _Float16* B0 = (_Float16*)alloc(NBUF * 2);
  _Float16* B1 = (_Float16*)alloc(NBUF * 2);
  _Float16* B2 = (_Float16*)alloc(NBUF * 2);
  _Float16* B3 = (_Float16*)alloc(NBUF * 2);
  _Float16* wp_c1 = (_Float16*)alloc((size_t)128 * 128 * 9 * 2);
  _Float16* wp_c2 = (_Float16*)alloc((size_t)128 * 128 * 9 * 2);
  const int sci[6] = {128, 32, 64, 128, 128, 64};
  const int sco[6] = {32, 64, 128, 128, 64, 32};
  _Float16* wp_d[6];
  for (int i = 0; i < 6; ++i) wp_d[i] = (_Float16*)alloc((size_t)sco[i] * sci[i] * 49 * 2);
  float* SUMS = (float*)alloc(8704 * 4);     // 8 layer slots x 1024 + md 512
  float* s_c1 = SUMS;
  float* s_c2 = SUMS + 1024;
  float* s_l[6];
  for (int i = 0; i < 6; ++i) s_l[i] = SUMS + 2048 + i * 1024;
  float* md   = SUMS + 8192;
  float* gate = (float*)alloc(512 * 4);
  float* wd   = (float*)alloc((size_t)HW2 * 4);
  float* sa   = (float*)alloc((size_t)4 * HW2 * 4);

  // ---- batched weight pack (ws re-poisoned each call -> redo) ----
  {
    WPackArgs p;
    p.src[0] = c1w; p.dst[0] = wp_c1; p.cout[0] = 128; p.cin[0] = 128; p.kk[0] = 3;
    p.src[1] = c2w; p.dst[1] = wp_c2; p.cout[1] = 128; p.cin[1] = 128; p.kk[1] = 3;
    for (int i = 0; i < 6; ++i) {
      p.src[2 + i] = dw[i]; p.dst[2 + i] = wp_d[i];
      p.cout[2 + i] = sco[i]; p.cin[2 + i] = sci[i]; p.kk[2 + i] = 7;
    }
    p.off[0] = 0;
    for (int i = 0; i < 8; ++i) p.off[i + 1] = p.off[i] + p.cout[i] * p.cin[i] * p.kk[i] * p.kk[i];
    wpack_all<<<(p.off[8] + 255) / 256, 256, 0, stream>>>(p);
  }

  to_nhwc<<<dim3(16384 / 64, 4, 4), 256, 0, stream>>>(x, B0, 128, 16384);
  zerok<<<34, 256, 0, stream>>>(SUMS, 8704);

  const float i1 = 1.f / (float)HW1, i2 = 1.f / (float)HW2, ib = 1.f / (4.f * HW2);

  // conv1: reflect 3x3, no input norm (bias cancels under IN); stats per-(b,c)
  conv_mfma<128, 128, 3, 128, 130, true, 0, false, true><<<dim3(9 * 17, 1, 4), 256, 0, stream>>>(
      B0, wp_c1, nullptr, nullptr, nullptr, 0.f, s_c1, B1);
  // conv2: stages IN(conv1)+relu inline; stats per-(b,c)
  conv_mfma<128, 128, 3, 130, 132, true, 1, true, true><<<dim3(9 * 17, 1, 4), 256, 0, stream>>>(
      B1, wp_c2, s_c1, nullptr, nullptr, i1, s_c2, B2);

  // SFOM (idct(g*dct(x)) == g*x algebraically; mean_k dct = analytic weights)
  wdctk<<<(HW2 + 255) / 256, 256, 0, stream>>>(wd, HW2);
  mdctk<<<dim3(128, 1, 4), 256, 0, stream>>>(B2, wd, s_c2, i2, md, HW2);
  gatek<<<1, 512, 0, stream>>>(md, sa_w1, sa_w2, gate);
  { size_t tot = (size_t)4 * HW2 * 16;
    sfomk<<<(int)((tot + 255) / 256), 256, 0, stream>>>(B2, s_c2, i2, gate, B3, HW2); }

  // SPEM pyramid: 7x7 convs, each staging applies previous BN+relu inline
  conv_mfma<128, 32, 7, 132, 132, false, 0, false, false><<<dim3(9 * 9, 1, 4), 256, 0, stream>>>(
      B3, wp_d[0], nullptr, nullptr, nullptr, 0.f, s_l[0], B0);
  conv_mfma<32, 64, 7, 132, 132, false, 2, true, false><<<dim3(9 * 17, 1, 4), 256, 0, stream>>>(
      B0, wp_d[1], s_l[0], bg[0], bb[0], ib, s_l[1], B1);
  conv_mfma<64, 128, 7, 132, 132, false, 2, true, false><<<dim3(9 * 17, 1, 4), 256, 0, stream>>>(
      B1, wp_d[2], s_l[1], bg[1], bb[1], ib, s_l[2], B0);
  conv_mfma<128, 128, 7, 132, 132, false, 2, true, false><<<dim3(9 * 17, 1, 4), 256, 0, stream>>>(
      B0, wp_d[3], s_l[2], bg[2], bb[2], ib, s_l[3], B1);
  conv_mfma<128, 64, 7, 132, 132, false, 2, true, false><<<dim3(9 * 17, 1, 4), 256, 0, stream>>>(
      B1, wp_d[4], s_l[3], bg[3], bb[3], ib, s_l[4], B0);
  conv_mfma<64, 32, 7, 132, 132, false, 2, true, false><<<dim3(9 * 9, 1, 4), 256, 0, stream>>>(
      B0, wp_d[5], s_l[4], bg[4], bb[4], ib, s_l[5], B1);

  // spatial attention (L6 BN+relu inline) + final product (NCHW f32 out)
  sak<<<(4 * HW2 + 255) / 256, 256, 0, stream>>>(B1, s_l[5], ib, bg[5], bb[5], cw, cb, sa);
  finalt<<<dim3((HW2 + 63) / 64, 4, 4), 256, 0, stream>>>(B3, sa, out);
}

// Round 7
// 902.870 us; speedup vs baseline: 1.3403x; 1.1663x over previous
//
#include <hip/hip_runtime.h>
#include <math.h>

#define B_    4
#define HW1   (130*130)
#define HW2   (132*132)
#define NBUF  ((size_t)B_*128*HW2)
#define EPS_  1e-5f
#define PI_   3.14159265358979f

typedef _Float16 half8 __attribute__((ext_vector_type(8)));
typedef _Float16 half4_ __attribute__((ext_vector_type(4)));
typedef float    float4_ __attribute__((ext_vector_type(4)));

// ============ batched weight pack: fp32 OIHW -> f16 [cc][tap][g][lane][8] ====
// lane=q*16+n ; co=g*16+n ; ci=cc*32+q*8+j  -> A-frag load is 1KB wave-contiguous
struct WPackArgs {
  const float* src[8];
  _Float16*    dst[8];
  int cout[8], cin[8], kk[8];
  int off[9];
};
__global__ void wpack_all(WPackArgs p) {
  int idx = blockIdx.x * blockDim.x + threadIdx.x;
  if (idx >= p.off[8]) return;
  int s = 0;
  while (idx >= p.off[s + 1]) ++s;
  int i = idx - p.off[s];
  int Cin = p.cin[s], K = p.kk[s];
  int KK = K * K, COG = p.cout[s] / 16;
  int j    = i & 7;
  int lane = (i >> 3) & 63;
  int rest = i >> 9;
  int g    = rest % COG; rest /= COG;
  int tap  = rest % KK;
  int cc   = rest / KK;
  int n = lane & 15, q = lane >> 4;
  int co = g * 16 + n;
  int ci = cc * 32 + q * 8 + j;
  p.dst[s][i] = (_Float16)p.src[s][((size_t)co * Cin + ci) * KK + tap];
}

// ============ NCHW f32 -> NHWC f16 (LDS transpose) ============
__global__ void to_nhwc(const float* __restrict__ in, _Float16* __restrict__ out,
                        int C, int HW) {
  __shared__ float t[32][65];
  int b = blockIdx.z, c0 = blockIdx.y * 32, p0 = blockIdx.x * 64;
  int tid = threadIdx.x;
  for (int i = 0; i < 8; ++i) {
    int e = i * 256 + tid; int cl = e >> 6, pl = e & 63;
    int p = p0 + pl;
    float v = 0.f;
    if (p < HW) v = in[((size_t)b * C + c0 + cl) * HW + p];
    t[cl][pl] = v;
  }
  __syncthreads();
  for (int i = 0; i < 8; ++i) {
    int e = i * 256 + tid; int pl = e >> 5, cl = e & 31;
    int p = p0 + pl;
    if (p < HW) out[((size_t)b * HW + p) * C + c0 + cl] = (_Float16)t[cl][pl];
  }
}

__global__ void zerok(float* p, int n) {
  int i = blockIdx.x * blockDim.x + threadIdx.x;
  if (i < n) p[i] = 0.f;
}

// ============ MFMA implicit-GEMM conv ============
// R4 pipeline (stage->barrier->compute, per-tap A 2-deep prefetch, B dbuf in
// 4-row half-groups) with NR=8 N-frags/wave for COUT>=64 (128-thr blocks):
// halves A-weight bytes per MFMA -- the measured co-limiter with MFMA issue.
// COUT=32 layers keep the R4 256-thr config.
template<int CIN, int COUT, int K, int HIN, int HOUT, bool REFLECT, int AFF, bool RELU, bool POB>
__global__ __launch_bounds__((COUT >= 64) ? 128 : 256, 2) void conv_mfma(
    const _Float16* __restrict__ act, const _Float16* __restrict__ wp,
    const float* __restrict__ sums_in, const float* __restrict__ gam,
    const float* __restrict__ bet, float invn, float* __restrict__ sums_out,
    _Float16* __restrict__ out) {
  constexpr int NT  = (COUT >= 64) ? 128 : 256;
  constexpr int NWAV = NT / 64;
  constexpr int NWC = (COUT >= 64) ? 2 : 1;
  constexpr int WCO = COUT / NWC;            // 64 / 32 / 32
  constexpr int MR  = WCO / 16;              // 4 / 2 / 2
  constexpr int NWR = NWAV / NWC;            // 1 / 1 / 4
  constexpr int NR  = (COUT >= 64) ? 8 : 4;  // N-frags per wave
  constexpr int NH  = NR / 4;                // 2 / 2 / 1 half-groups
  constexpr int ROWS = NWR * NR;             // 8 / 8 / 16
  constexpr int PADc = (K - 1) / 2;
  constexpr int IR  = ROWS + K - 1;
  constexpr int XW  = 16 + K - 1;            // 22 / 18
  constexpr int CH  = IR * 4 * XW;           // 16B chunks, idx (row*4+q)*XW+x
  constexpr int COG = COUT / 16;
  constexpr int KK  = K * K;
  constexpr int XT  = (HOUT + 15) / 16;

  __shared__ half8 smem[CH];
  __shared__ float2 snorm[CIN];
  __shared__ float bsum[COUT * 2];

  const int xt = blockIdx.x % XT, yt = blockIdx.x / XT;
  const int x0 = xt * 16, y0 = yt * ROWS;
  const int b = blockIdx.z;
  const int tid = threadIdx.x;
  const int lane = tid & 63, w = tid >> 6;
  const int wc = (NWC == 2) ? w : 0;
  const int wr = (NWC == 2) ? 0 : w;
  const int n = lane & 15, q = lane >> 4;

  // ---- preamble: inline norm params + zero block stats ----
  if (AFF) {
    if (tid < CIN) {
      int idx = (AFF == 1 ? b * CIN : 0) + tid;
      float m  = sums_in[idx * 2] * invn;
      float vr = sums_in[idx * 2 + 1] * invn - m * m;
      float sc = rsqrtf(vr + EPS_);
      if (AFF == 2) sc *= gam[tid];
      float sh = (AFF == 2 ? bet[tid] : 0.f) - m * sc;
      snorm[tid] = make_float2(sc, sh);
    }
  }
  if (tid < COUT) { bsum[tid * 2] = 0.f; bsum[tid * 2 + 1] = 0.f; }

  float4_ acc[MR][NR];
#pragma unroll
  for (int mi = 0; mi < MR; ++mi)
#pragma unroll
    for (int ni = 0; ni < NR; ++ni)
#pragma unroll
      for (int j = 0; j < 4; ++j) acc[mi][ni][j] = 0.f;

  const _Float16* actb = act + (size_t)b * HIN * HIN * CIN;

  for (int cc = 0; cc < CIN / 32; ++cc) {
    __syncthreads();
    // ---- per-thread norm regs (qq = tid&3 fixed across staging elements) ----
    float nsc[8], nsh[8];
    if (AFF) {
      int cb2 = cc * 32 + (tid & 3) * 8;
#pragma unroll
      for (int j = 0; j < 8; ++j) { float2 t = snorm[cb2 + j]; nsc[j] = t.x; nsh[j] = t.y; }
    }
    // ---- stage (affine+relu applied; borders stay zero = conv zero-pad) ----
    for (int e = tid; e < CH; e += NT) {
      int qq = e & 3, rx = e >> 2;
      int row = rx / XW, lx = rx % XW;
      int ty = y0 + row - PADc;
      int tx = x0 + lx - PADc;
      bool ok; int iy, ix;
      if (REFLECT) {   // P-space; P = reflect_pad1(x), conv pad=1 zeros outside
        ok = (ty >= 0 && ty < HIN + 2 && tx >= 0 && tx < HIN + 2);
        iy = (ty == 0) ? 1 : (ty == HIN + 1 ? HIN - 2 : ty - 1);
        ix = (tx == 0) ? 1 : (tx == HIN + 1 ? HIN - 2 : tx - 1);
      } else {
        ok = (ty >= 0 && ty < HIN && tx >= 0 && tx < HIN);
        iy = ty; ix = tx;
      }
      half8 v;
#pragma unroll
      for (int j = 0; j < 8; ++j) v[j] = (_Float16)0.f;
      if (ok) {
        v = *(const half8*)(actb + ((size_t)iy * HIN + ix) * CIN + cc * 32 + qq * 8);
        if (AFF) {
#pragma unroll
          for (int j = 0; j < 8; ++j) {
            float f = (float)v[j] * nsc[j] + nsh[j];
            if (RELU) f = fmaxf(f, 0.f);
            v[j] = (_Float16)f;
          }
        }
      }
      smem[(row * 4 + qq) * XW + lx] = v;
    }
    __syncthreads();
    // ---- compute: per-tap A 2-deep prefetch; B dbuf in 4-row half-groups ----
    {
      auto ldA = [&](int tap, half8* a) {
#pragma unroll
        for (int mi = 0; mi < MR; ++mi) {
          int g = wc * MR + mi;
          a[mi] = *(const half8*)(wp + (((size_t)(cc * KK + tap) * COG + g) * 64 + lane) * 8);
        }
      };
      auto ldBh = [&](int tap, int h, half8* c) {
        int ky = tap / K, kx = tap % K;
        int rbase = wr * NR + h * 4 + ky;
#pragma unroll
        for (int ni = 0; ni < 4; ++ni)
          c[ni] = smem[((rbase + ni) * 4 + q) * XW + n + kx];
      };
      auto domfh = [&](half8* a, half8* c, int h) {
#pragma unroll
        for (int mi = 0; mi < MR; ++mi)
#pragma unroll
          for (int ni = 0; ni < 4; ++ni)
            acc[mi][h * 4 + ni] = __builtin_amdgcn_mfma_f32_16x16x32_f16(
                a[mi], c[ni], acc[mi][h * 4 + ni], 0, 0, 0);
      };
      half8 a0[MR], a1[MR], c0[4], c1[4];
      ldA(0, a0);
      ldA(1, a1);
      ldBh(0, 0, c0);
      for (int tap = 0; tap + 1 < KK; tap += 2) {   // KK odd: tap+2 <= KK-1 inside
        if constexpr (NH == 2) {
          ldBh(tap, 1, c1);
          domfh(a0, c0, 0);
          ldBh(tap + 1, 0, c0);
          domfh(a0, c1, 1);
          ldA(tap + 2, a0);
          ldBh(tap + 1, 1, c1);
          domfh(a1, c0, 0);
          ldBh(tap + 2, 0, c0);
          domfh(a1, c1, 1);
          if (tap + 3 < KK) ldA(tap + 3, a1);
        } else {
          ldBh(tap + 1, 0, c1);
          domfh(a0, c0, 0);
          ldA(tap + 2, a0);
          ldBh(tap + 2, 0, c0);
          domfh(a1, c1, 0);
          if (tap + 3 < KK) ldA(tap + 3, a1);
        }
      }
      if constexpr (NH == 2) {                      // tail tap = KK-1
        ldBh(KK - 1, 1, c1);
        domfh(a0, c0, 0);
        domfh(a0, c1, 1);
      } else {
        domfh(a0, c0, 0);
      }
    }
  }

  // ---- epilogue 1: per-co stats from f32 accumulators ----
  const bool xv = (x0 + n) < HOUT;
#pragma unroll
  for (int mi = 0; mi < MR; ++mi) {
#pragma unroll
    for (int j = 0; j < 4; ++j) {
      float s = 0.f, s2 = 0.f;
#pragma unroll
      for (int ni = 0; ni < NR; ++ni) {
        int y = y0 + wr * NR + ni;
        float f = acc[mi][ni][j];
        bool v = xv && (y < HOUT);
        s  += v ? f : 0.f;
        s2 += v ? f * f : 0.f;
      }
#pragma unroll
      for (int off = 1; off < 16; off <<= 1) {    // reduce across the 16 n-lanes
        s  += __shfl_xor(s,  off, 64);
        s2 += __shfl_xor(s2, off, 64);
      }
      if (n == 0) {
        int co = wc * WCO + mi * 16 + q * 4 + j;
        atomicAdd(&bsum[co * 2],     s);
        atomicAdd(&bsum[co * 2 + 1], s2);
      }
    }
  }
  // ---- epilogue 2: store NHWC f16 (raw conv out; norm applied by consumer) ----
  _Float16* outb = out + (size_t)b * HOUT * HOUT * COUT;
#pragma unroll
  for (int mi = 0; mi < MR; ++mi) {
#pragma unroll
    for (int ni = 0; ni < NR; ++ni) {
      int y = y0 + wr * NR + ni, x = x0 + n;
      if (y < HOUT && x < HOUT) {
        int co = wc * WCO + mi * 16 + q * 4;
        half4_ h;
#pragma unroll
        for (int j = 0; j < 4; ++j) h[j] = (_Float16)acc[mi][ni][j];
        *(half4_*)(outb + ((size_t)y * HOUT + x) * COUT + co) = h;
      }
    }
  }
  __syncthreads();
  if (tid < COUT) {
    int idx = (POB ? b * COUT : 0) + tid;
    atomicAdd(&sums_out[idx * 2],     bsum[tid * 2]);
    atomicAdd(&sums_out[idx * 2 + 1], bsum[tid * 2 + 1]);
  }
}

// ============ analytic DCT-mean weights ============
__global__ void wdctk(float* __restrict__ wd, int N) {
  int i = blockIdx.x * blockDim.x + threadIdx.x;
  if (i >= N) return;
  float Nf = (float)N;
  float c2 = 0.5f * sqrtf(2.f / Nf);
  float a  = sqrtf(1.f / Nf) - c2;
  float phi = PI_ / (4.f * Nf) * (2.f * i + 1.f);
  float cot = cosf(phi) / sinf(phi);
  wd[i] = a + ((i & 1) ? -c2 : c2) * cot;
}

// ============ md[b][c] += sum_p wd[p]*IN(x)  (inline norm from sums2) ============
__global__ void mdctk(const _Float16* __restrict__ x, const float* __restrict__ wd,
                      const float* __restrict__ sums2, float invn,
                      float* __restrict__ md, int HW) {
  int b = blockIdx.z, tid = threadIdx.x;
  int c = tid & 127, pr = tid >> 7;
  int slab = blockIdx.x, nsl = gridDim.x;
  float m  = sums2[(b * 128 + c) * 2] * invn;
  float sc = rsqrtf(sums2[(b * 128 + c) * 2 + 1] * invn - m * m + EPS_);
  float sh = -m * sc;
  const _Float16* xb = x + (size_t)b * HW * 128;
  float s = 0.f;
  for (int p = slab * 2 + pr; p < HW; p += nsl * 2)
    s += ((float)xb[(size_t)p * 128 + c] * sc + sh) * wd[p];
  __shared__ float l1[256];
  l1[tid] = s;
  __syncthreads();
  if (tid < 128) atomicAdd(&md[b * 128 + c], l1[tid] + l1[tid + 128]);
}

// ============ SFOM gate MLP ============
__global__ void gatek(const float* __restrict__ md, const float* __restrict__ w1,
                      const float* __restrict__ w2, float* __restrict__ gate) {
  __shared__ float t1[4][8];
  int tid = threadIdx.x;
  const float invN = 1.f / (float)HW2;
  if (tid < 32) {
    int b = tid >> 3, r = tid & 7;
    float s = 0.f;
    for (int c = 0; c < 128; ++c) s += md[b * 128 + c] * invN * w1[r * 128 + c];
    t1[b][r] = fmaxf(s, 0.f);
  }
  __syncthreads();
  int b = tid >> 7, c = tid & 127;
  float s = 0.f;
#pragma unroll
  for (int r = 0; r < 8; ++r) s += t1[b][r] * w2[c * 8 + r];
  gate[tid] = 1.f / (1.f + expf(-s));
}

// ============ SFOM apply: xn = IN(x); o = sigmoid(xn*(1+g)/2)*xn ============
__global__ void sfomk(const _Float16* __restrict__ x, const float* __restrict__ sums2,
                      float invn, const float* __restrict__ gate,
                      _Float16* __restrict__ o, int HW) {
  size_t idx = (size_t)blockIdx.x * blockDim.x + threadIdx.x;
  size_t tot = (size_t)4 * HW * 16;
  if (idx >= tot) return;
  int cg = (int)(idx % 16);
  size_t bp = idx / 16;
  int b = (int)(bp / HW);
  half8 v = *(const half8*)(x + bp * 128 + cg * 8);
  half8 r;
#pragma unroll
  for (int j = 0; j < 8; ++j) {
    int c = cg * 8 + j;
    float m  = sums2[(b * 128 + c) * 2] * invn;
    float sc = rsqrtf(sums2[(b * 128 + c) * 2 + 1] * invn - m * m + EPS_);
    float f = (float)v[j] * sc - m * sc;
    float g = gate[b * 128 + c];
    float s = 1.f / (1.f + expf(-(f * (1.f + g) * 0.5f)));
    r[j] = (_Float16)(s * f);
  }
  *(half8*)(o + bp * 128 + cg * 8) = r;
}

// ============ sa = sigmoid(b + sum_c cw[c]*relu(BN(h)))  (inline from sums6) ====
__global__ void sak(const _Float16* __restrict__ h, const float* __restrict__ sums6,
                    float invn, const float* __restrict__ gam, const float* __restrict__ bet,
                    const float* __restrict__ cw, const float* __restrict__ cb,
                    float* __restrict__ sa) {
  __shared__ float ssc[32], ssh[32];
  int tid = threadIdx.x;
  if (tid < 32) {
    float m  = sums6[tid * 2] * invn;
    float sc = rsqrtf(sums6[tid * 2 + 1] * invn - m * m + EPS_) * gam[tid];
    ssc[tid] = sc;
    ssh[tid] = bet[tid] - m * sc;
  }
  __syncthreads();
  int idx = blockIdx.x * blockDim.x + tid;
  if (idx >= 4 * HW2) return;
  const _Float16* p = h + (size_t)idx * 32;
  float s = cb[0];
#pragma unroll
  for (int c = 0; c < 32; ++c)
    s += fmaxf((float)p[c] * ssc[c] + ssh[c], 0.f) * cw[c];
  sa[idx] = 1.f / (1.f + expf(-s));
}

// ============ final: NCHW f32 out = sa * O (NHWC f16), LDS transpose ============
__global__ void finalt(const _Float16* __restrict__ o, const float* __restrict__ sa,
                       float* __restrict__ out) {
  __shared__ float t[32][65];
  int b = blockIdx.z, c0 = blockIdx.y * 32, p0 = blockIdx.x * 64;
  int tid = threadIdx.x;
  for (int i = 0; i < 8; ++i) {
    int e = i * 256 + tid; int pl = e >> 5, cl = e & 31;
    int p = p0 + pl;
    if (p < HW2)
      t[cl][pl] = (float)o[((size_t)b * HW2 + p) * 128 + c0 + cl] * sa[b * HW2 + p];
  }
  __syncthreads();
  for (int i = 0; i < 8; ++i) {
    int e = i * 256 + tid; int cl = e >> 6, pl = e & 63;
    int p = p0 + pl;
    if (p < HW2)
      out[((size_t)b * 128 + c0 + cl) * HW2 + p] = t[cl][pl];
  }
}

extern "C" void kernel_launch(void* const* d_in, const int* in_sizes, int n_in,
                              void* d_out, int out_size, void* d_ws, size_t ws_size,
                              hipStream_t stream) {
  const float* x     = (const float*)d_in[0];
  const float* c1w   = (const float*)d_in[1];
  const float* c2w   = (const float*)d_in[3];
  const float* sa_w1 = (const float*)d_in[5];
  const float* sa_w2 = (const float*)d_in[6];
  const float* dw[6] = {(const float*)d_in[7],  (const float*)d_in[10], (const float*)d_in[13],
                        (const float*)d_in[16], (const float*)d_in[19], (const float*)d_in[22]};
  const float* bg[6] = {(const float*)d_in[8],  (const float*)d_in[11], (const float*)d_in[14],
                        (const float*)d_in[17], (const float*)d_in[20], (const float*)d_in[23]};
  const float* bb[6] = {(const float*)d_in[9],  (const float*)d_in[12], (const float*)d_in[15],
                        (const float*)d_in[18], (const float*)d_in[21], (const float*)d_in[24]};
  const float* cw    = (const float*)d_in[25];
  const float* cb    = (const float*)d_in[26];
  float* out = (float*)d_out;

  // ---- workspace carve ----
  char* wsp = (char*)d_ws;
  auto alloc = [&](size_t bytes) { char* p = wsp; wsp += (bytes + 255) & ~(size_t)255; return p; };
  _Float16* B0 = (_Float16*)alloc(NBUF * 2);
  _Float16* B1 = (_Float16*)alloc(NBUF * 2);
  _Float16* B2 = (_Float16*)alloc(NBUF * 2);
  _Float16* B3 = (_Float16*)alloc(NBUF * 2);
  _Float16* wp_c1 = (_Float16*)alloc((size_t)128 * 128 * 9 * 2);
  _Float16* wp_c2 = (_Float16*)alloc((size_t)128 * 128 * 9 * 2);
  const int sci[6] = {128, 32, 64, 128, 128, 64};
  const int sco[6] = {32, 64, 128, 128, 64, 32};
  _Float16* wp_d[6];
  for (int i = 0; i < 6; ++i) wp_d[i] = (_Float16*)alloc((size_t)sco[i] * sci[i] * 49 * 2);
  float* SUMS = (float*)alloc(8704 * 4);     // 8 layer slots x 1024 + md 512
  float* s_c1 = SUMS;
  float* s_c2 = SUMS + 1024;
  float* s_l[6];
  for (int i = 0; i < 6; ++i) s_l[i] = SUMS + 2048 + i * 1024;
  float* md   = SUMS + 8192;
  float* gate = (float*)alloc(512 * 4);
  float* wd   = (float*)alloc((size_t)HW2 * 4);
  float* sa   = (float*)alloc((size_t)4 * HW2 * 4);

  // ---- batched weight pack (ws re-poisoned each call -> redo) ----
  {
    WPackArgs p;
    p.src[0] = c1w; p.dst[0] = wp_c1; p.cout[0] = 128; p.cin[0] = 128; p.kk[0] = 3;
    p.src[1] = c2w; p.dst[1] = wp_c2; p.cout[1] = 128; p.cin[1] = 128; p.kk[1] = 3;
    for (int i = 0; i < 6; ++i) {
      p.src[2 + i] = dw[i]; p.dst[2 + i] = wp_d[i];
      p.cout[2 + i] = sco[i]; p.cin[2 + i] = sci[i]; p.kk[2 + i] = 7;
    }
    p.off[0] = 0;
    for (int i = 0; i < 8; ++i) p.off[i + 1] = p.off[i] + p.cout[i] * p.cin[i] * p.kk[i] * p.kk[i];
    wpack_all<<<(p.off[8] + 255) / 256, 256, 0, stream>>>(p);
  }

  to_nhwc<<<dim3(16384 / 64, 4, 4), 256, 0, stream>>>(x, B0, 128, 16384);
  zerok<<<34, 256, 0, stream>>>(SUMS, 8704);

  const float i1 = 1.f / (float)HW1, i2 = 1.f / (float)HW2, ib = 1.f / (4.f * HW2);

  // conv1: reflect 3x3, no input norm (bias cancels under IN); stats per-(b,c)
  conv_mfma<128, 128, 3, 128, 130, true, 0, false, true><<<dim3(9 * 17, 1, 4), 128, 0, stream>>>(
      B0, wp_c1, nullptr, nullptr, nullptr, 0.f, s_c1, B1);
  // conv2: stages IN(conv1)+relu inline; stats per-(b,c)
  conv_mfma<128, 128, 3, 130, 132, true, 1, true, true><<<dim3(9 * 17, 1, 4), 128, 0, stream>>>(
      B1, wp_c2, s_c1, nullptr, nullptr, i1, s_c2, B2);

  // SFOM (idct(g*dct(x)) == g*x algebraically; mean_k dct = analytic weights)
  wdctk<<<(HW2 + 255) / 256, 256, 0, stream>>>(wd, HW2);
  mdctk<<<dim3(128, 1, 4), 256, 0, stream>>>(B2, wd, s_c2, i2, md, HW2);
  gatek<<<1, 512, 0, stream>>>(md, sa_w1, sa_w2, gate);
  { size_t tot = (size_t)4 * HW2 * 16;
    sfomk<<<(int)((tot + 255) / 256), 256, 0, stream>>>(B2, s_c2, i2, gate, B3, HW2); }

  // SPEM pyramid: 7x7 convs, each staging applies previous BN+relu inline
  conv_mfma<128, 32, 7, 132, 132, false, 0, false, false><<<dim3(9 * 9, 1, 4), 256, 0, stream>>>(
      B3, wp_d[0], nullptr, nullptr, nullptr, 0.f, s_l[0], B0);
  conv_mfma<32, 64, 7, 132, 132, false, 2, true, false><<<dim3(9 * 17, 1, 4), 128, 0, stream>>>(
      B0, wp_d[1], s_l[0], bg[0], bb[0], ib, s_l[1], B1);
  conv_mfma<64, 128, 7, 132, 132, false, 2, true, false><<<dim3(9 * 17, 1, 4), 128, 0, stream>>>(
      B1, wp_d[2], s_l[1], bg[1], bb[1], ib, s_l[2], B0);
  conv_mfma<128, 128, 7, 132, 132, false, 2, true, false><<<dim3(9 * 17, 1, 4), 128, 0, stream>>>(
      B0, wp_d[3], s_l[2], bg[2], bb[2], ib, s_l[3], B1);
  conv_mfma<128, 64, 7, 132, 132, false, 2, true, false><<<dim3(9 * 17, 1, 4), 128, 0, stream>>>(
      B1, wp_d[4], s_l[3], bg[3], bb[3], ib, s_l[4], B0);
  conv_mfma<64, 32, 7, 132, 132, false, 2, true, false><<<dim3(9 * 9, 1, 4), 256, 0, stream>>>(
      B0, wp_d[5], s_l[4], bg[4], bb[4], ib, s_l[5], B1);

  // spatial attention (L6 BN+relu inline) + final product (NCHW f32 out)
  sak<<<(4 * HW2 + 255) / 256, 256, 0, stream>>>(B1, s_l[5], ib, bg[5], bb[5], cw, cb, sa);
  finalt<<<dim3((HW2 + 63) / 64, 4, 4), 256, 0, stream>>>(B3, sa, out);
}